// Round 4
// baseline (312.141 us; speedup 1.0000x reference)
//
#include <hip/hip_runtime.h>
#include <hip/hip_bf16.h>
#include <math.h>

#define DMODEL 512
#define DINNER 1024
#define DSTATE 16
#define SEQLEN 2048
#define NTOK   4096
#define CHUNK  64
#define NCHUNK (SEQLEN / CHUNK)  // 32

#define BM 128
#define BN 64
#define BK 64

typedef __bf16 bf16x8 __attribute__((ext_vector_type(8)));
typedef float  f32x4  __attribute__((ext_vector_type(4)));

__device__ __forceinline__ float silu_f(float x) {
    return x / (1.0f + __expf(-x));
}

// swizzled LDS index (bf16 elems) for row r, 16B slot s (8 slots per 64-elem row)
__device__ __forceinline__ int swz(int r, int s) {
    return r * BK + ((s ^ (r & 7)) << 3);
}

// ---------------------------------------------------------------------------
// bf16 MFMA GEMM, tile 128x64, BK=64, 4 waves (each 64x32 = 4x2 frags).
// Reg-staged LDS with XOR swizzle; next-tile loads issued before MFMA phase.
// MODE 1: conv  — A rows shifted by (k0>>9)-1, batch-aware zero pad;
//                 epilogue silu(acc+bias[n]) -> C0 f32 + Cb bf16
// MODE 2: delta — epilogue softplus(acc+bias[n]) * xc[m,n] * 0.95^(l+1) -> C0
// MODE 3: plain — C0 = acc (f32)
// MODE 4: fused-weight GEMM — per-tap (blockIdx.z), bf16 store at ldc stride
// ---------------------------------------------------------------------------
template<int MODE>
__global__ __launch_bounds__(256)
void mgemm(const __hip_bfloat16* __restrict__ A, int lda,
           const __hip_bfloat16* __restrict__ WT, int ldw,
           float* __restrict__ C0, __hip_bfloat16* __restrict__ Cb, int ldc,
           int K, const float* __restrict__ bias, const float* __restrict__ xc)
{
    __shared__ __align__(16) __hip_bfloat16 As[BM * BK];  // 16 KB
    __shared__ __align__(16) __hip_bfloat16 Bs[BN * BK];  // 8 KB

    // bijective XCD swizzle (all launches have nb % 8 == 0)
    const int nb  = gridDim.x * gridDim.y;
    const int lin = blockIdx.y * gridDim.x + blockIdx.x;
    const int cpx = nb >> 3;
    const int sl  = (lin & 7) * cpx + (lin >> 3);
    const int bm  = (sl / gridDim.x) * BM;
    const int bn  = (sl % gridDim.x) * BN;

    if (MODE == 4) { A += blockIdx.z * 1024; Cb += blockIdx.z * 512; }

    const int tid  = threadIdx.x;
    const int srow = tid >> 3, sslot = tid & 7;
    const int wid  = tid >> 6, lane = tid & 63;
    const int wr   = (wid >> 1) * 64, wc = (wid & 1) * 32;
    const int llo  = lane & 15, lhi = lane >> 4;

    f32x4 acc[4][2] = {};
    int4 ra[4], rb[2];

    auto load_tile = [&](int k0) {
#pragma unroll
        for (int p = 0; p < 4; ++p) {
            int r = srow + p * 32;
            if (MODE == 1) {
                int kid = k0 >> 9;                 // tap index (512 K per tap)
                int gr  = bm + r;
                int l2  = (gr & (SEQLEN - 1)) + kid - 1;
                if ((unsigned)l2 < (unsigned)SEQLEN)
                    ra[p] = *reinterpret_cast<const int4*>(
                        A + (size_t)(gr + kid - 1) * lda + (k0 & 511) + sslot * 8);
                else
                    ra[p] = make_int4(0, 0, 0, 0);
            } else {
                ra[p] = *reinterpret_cast<const int4*>(
                    A + (size_t)(bm + srow + p * 32) * lda + k0 + sslot * 8);
            }
        }
#pragma unroll
        for (int p = 0; p < 2; ++p) {
            rb[p] = *reinterpret_cast<const int4*>(
                WT + (size_t)(bn + srow + p * 32) * ldw + k0 + sslot * 8);
        }
    };

    const int NT = K / BK;
    load_tile(0);
    for (int t = 0; t < NT; ++t) {
        // stage tile t (swizzled) — compiler inserts vmcnt wait on ra/rb
#pragma unroll
        for (int p = 0; p < 4; ++p)
            *reinterpret_cast<int4*>(&As[swz(srow + p * 32, sslot)]) = ra[p];
#pragma unroll
        for (int p = 0; p < 2; ++p)
            *reinterpret_cast<int4*>(&Bs[swz(srow + p * 32, sslot)]) = rb[p];
        __syncthreads();
        if (t + 1 < NT) load_tile((t + 1) * BK);   // in flight under MFMA phase
#pragma unroll
        for (int kk = 0; kk < BK; kk += 32) {
            bf16x8 af[4], bv[2];
#pragma unroll
            for (int i = 0; i < 4; ++i)
                af[i] = *reinterpret_cast<const bf16x8*>(&As[swz(wr + i * 16 + llo, (kk >> 3) + lhi)]);
#pragma unroll
            for (int j = 0; j < 2; ++j)
                bv[j] = *reinterpret_cast<const bf16x8*>(&Bs[swz(wc + j * 16 + llo, (kk >> 3) + lhi)]);
#pragma unroll
            for (int i = 0; i < 4; ++i)
#pragma unroll
                for (int j = 0; j < 2; ++j)
                    acc[i][j] = __builtin_amdgcn_mfma_f32_16x16x32_bf16(af[i], bv[j], acc[i][j], 0, 0, 0);
        }
        __syncthreads();
    }

#pragma unroll
    for (int i = 0; i < 4; ++i) {
#pragma unroll
        for (int q = 0; q < 4; ++q) {
            int m = bm + wr + i * 16 + lhi * 4 + q;
            float dec = 1.0f;
            if (MODE == 2)
                dec = __expf((float)((m & (SEQLEN - 1)) + 1) * -0.051293294f); // ln 0.95
#pragma unroll
            for (int j = 0; j < 2; ++j) {
                int n = bn + wc + j * 16 + llo;
                float v = acc[i][j][q];
                if (MODE == 1) {
                    v = silu_f(v + bias[n]);
                    C0[(size_t)m * ldc + n] = v;
                    Cb[(size_t)m * ldc + n] = __float2bfloat16(v);
                } else if (MODE == 2) {
                    float d  = v + bias[n];
                    float sp = fmaxf(d, 0.f) + log1pf(__expf(-fabsf(d)));
                    C0[(size_t)m * ldc + n] = sp * xc[(size_t)m * DINNER + n] * dec;
                } else if (MODE == 4) {
                    Cb[(size_t)m * ldc + n] = __float2bfloat16(v);
                } else {
                    C0[(size_t)m * ldc + n] = v;
                }
            }
        }
    }
}

// transpose + f32->bf16: out[c][r] = in[r*ldin + c]
__global__ __launch_bounds__(256)
void transpose_bf16_k(const float* __restrict__ in, __hip_bfloat16* __restrict__ out,
                      int R, int C, int ldin)
{
    __shared__ float t[32][33];
    int bx = blockIdx.x * 32, by = blockIdx.y * 32;
    int tx = threadIdx.x & 31, ty = threadIdx.x >> 5;
#pragma unroll
    for (int q = 0; q < 4; ++q)
        t[ty + q * 8][tx] = in[(size_t)(by + ty + q * 8) * ldin + bx + tx];
    __syncthreads();
#pragma unroll
    for (int q = 0; q < 4; ++q)
        out[(size_t)(bx + ty + q * 8) * R + by + tx] = __float2bfloat16(t[tx][ty + q * 8]);
}

// f32 -> bf16, first C cols of each row (ldin-strided source)
__global__ __launch_bounds__(256)
void cvt_slice_k(const float* __restrict__ in, __hip_bfloat16* __restrict__ out,
                 int ldin, int c4cnt)
{
    int idx = blockIdx.x * 256 + threadIdx.x;
    int r = idx / c4cnt, c = (idx - r * c4cnt) * 4;
    float4 v = *reinterpret_cast<const float4*>(in + (size_t)r * ldin + c);
    __hip_bfloat16 tmp[4] = {__float2bfloat16(v.x), __float2bfloat16(v.y),
                             __float2bfloat16(v.z), __float2bfloat16(v.w)};
    *reinterpret_cast<ushort4*>(&out[(size_t)r * (c4cnt * 4) + c]) =
        *reinterpret_cast<const ushort4*>(tmp);
}

// Bm = xc@wB + bB ; Cm = xc@wC + bC   (one token per block)
__global__ __launch_bounds__(256)
void bc_k(const float* __restrict__ xc,
          const float* __restrict__ wB, const float* __restrict__ bB,
          const float* __restrict__ wC, const float* __restrict__ bC,
          float* __restrict__ Bm, float* __restrict__ Cm)
{
    __shared__ float xr[DINNER];
    __shared__ float part[8][32];
    int t = blockIdx.x;
    int tid = threadIdx.x;
#pragma unroll
    for (int q = 0; q < 4; ++q) {
        int i = tid + q * 256;
        xr[i] = xc[(size_t)t * DINNER + i];
    }
    __syncthreads();
    int s = tid & 31;
    int p = tid >> 5;
    const float* W = (s < 16) ? wB : wC;
    int col = s & 15;
    float acc = 0.f;
    for (int k = p * 128; k < p * 128 + 128; ++k)
        acc += xr[k] * W[k * DSTATE + col];
    part[p][s] = acc;
    __syncthreads();
    if (tid < 32) {
        float sum = 0.f;
#pragma unroll
        for (int pp = 0; pp < 8; ++pp) sum += part[pp][tid];
        if (tid < 16) Bm[(size_t)t * DSTATE + tid] = sum + bB[tid];
        else          Cm[(size_t)t * DSTATE + (tid - 16)] = sum + bC[tid - 16];
    }
}

// per-chunk state S[bc][n][s] = sum_{t in chunk} w[t,n]*Bm[t,s]
__global__ __launch_bounds__(256)
void chunkS_k(const float* __restrict__ w, const float* __restrict__ Bm,
              float* __restrict__ S)
{
    int bc = blockIdx.x;
    int n0 = blockIdx.y * 16;
    int t0 = bc * CHUNK;
    __shared__ float wsh[CHUNK][16];
    __shared__ float bsh[CHUNK][17];
    int tid = threadIdx.x;
#pragma unroll
    for (int q = 0; q < 4; ++q) {
        int lin = tid + q * 256;
        int j = lin >> 4, col = lin & 15;
        wsh[j][col] = w[(size_t)(t0 + j) * DINNER + n0 + col];
        bsh[j][col] = Bm[(size_t)(t0 + j) * DSTATE + col];
    }
    __syncthreads();
    int ni = tid & 15, s = tid >> 4;
    float acc = 0.f;
#pragma unroll
    for (int j = 0; j < CHUNK; ++j)
        acc += wsh[j][ni] * bsh[j][s];
    S[((size_t)bc * DINNER + n0 + ni) * DSTATE + s] = acc;
}

// exclusive prefix over chunks
__global__ __launch_bounds__(256)
void hpre_k(const float* __restrict__ S, float* __restrict__ H)
{
    int idx = blockIdx.x * 256 + threadIdx.x;
    int b  = idx >> 14;
    int ns = idx & 16383;
    float acc = 0.f;
    for (int c = 0; c < NCHUNK; ++c) {
        size_t off = ((size_t)(b * NCHUNK + c)) * (DINNER * DSTATE) + ns;
        H[off] = acc;
        acc += S[off];
    }
}

// intra-chunk + inter combine + gate -> gb (bf16)
__global__ __launch_bounds__(256)
void intra_k(const float* __restrict__ wbuf,
             const float* __restrict__ Bm, const float* __restrict__ Cm,
             const float* __restrict__ H,
             const float* __restrict__ zbuf,
             __hip_bfloat16* __restrict__ gb)
{
    int bc = blockIdx.x;
    int t0 = bc * CHUNK;
    int n0 = blockIdx.y * 64;
    __shared__ float wsh[CHUNK][65];
    __shared__ float Psh[CHUNK][CHUNK + 1];
    __shared__ float bsh[CHUNK][17];
    __shared__ float csh[CHUNK][17];
    int tid = threadIdx.x;
#pragma unroll
    for (int q = 0; q < 16; ++q) {
        int lin = tid + q * 256;
        int j = lin >> 6, col = lin & 63;
        wsh[j][col] = wbuf[(size_t)(t0 + j) * DINNER + n0 + col];
    }
#pragma unroll
    for (int q = 0; q < 4; ++q) {
        int lin = tid + q * 256;
        int j = lin >> 4, sc = lin & 15;
        bsh[j][sc] = Bm[(size_t)(t0 + j) * DSTATE + sc];
        csh[j][sc] = Cm[(size_t)(t0 + j) * DSTATE + sc];
    }
    __syncthreads();
#pragma unroll
    for (int q = 0; q < 16; ++q) {
        int lin = tid + q * 256;
        int l = lin >> 6, t = lin & 63;
        float p = 0.f;
#pragma unroll
        for (int s = 0; s < DSTATE; ++s) p += csh[l][s] * bsh[t][s];
        Psh[l][t] = p;
    }
    __syncthreads();
    int n  = tid & 63;
    int lg = tid >> 6;
    float hv[DSTATE];
#pragma unroll
    for (int s = 0; s < DSTATE; ++s)
        hv[s] = H[(size_t)bc * (DINNER * DSTATE) + (size_t)(n0 + n) * DSTATE + s];
#pragma unroll
    for (int q = 0; q < 16; ++q) {
        int l = lg * 16 + q;
        float y = 0.f;
#pragma unroll
        for (int s = 0; s < DSTATE; ++s) y += hv[s] * csh[l][s];
        for (int t = 0; t <= l; ++t) y += Psh[l][t] * wsh[t][n];
        int token = t0 + l;
        float z = zbuf[(size_t)token * DINNER + n0 + n];
        gb[(size_t)token * DINNER + n0 + n] = __float2bfloat16(y * silu_f(z));
    }
}

extern "C" void kernel_launch(void* const* d_in, const int* in_sizes, int n_in,
                              void* d_out, int out_size, void* d_ws, size_t ws_size,
                              hipStream_t stream) {
    const float* x      = (const float*)d_in[0];
    const float* w_in   = (const float*)d_in[1];
    const float* conv_k = (const float*)d_in[2];
    const float* conv_b = (const float*)d_in[3];
    const float* w_del  = (const float*)d_in[4];
    const float* b_del  = (const float*)d_in[5];
    const float* w_B    = (const float*)d_in[6];
    const float* b_B    = (const float*)d_in[7];
    const float* w_C    = (const float*)d_in[8];
    const float* b_C    = (const float*)d_in[9];
    const float* w_out  = (const float*)d_in[11];
    float* out = (float*)d_out;

    float* zbuf  = (float*)d_ws;                          // 4M f32
    float* xconv = zbuf  + (size_t)NTOK * DINNER;         // 4M
    float* wbuf  = xconv + (size_t)NTOK * DINNER;         // 4M
    float* Bm    = wbuf  + (size_t)NTOK * DINNER;
    float* Cm    = Bm    + (size_t)NTOK * DSTATE;
    float* S     = Cm    + (size_t)NTOK * DSTATE;         // 1M
    float* H     = S     + (size_t)2 * NCHUNK * DINNER * DSTATE;  // 1M
    __hip_bfloat16* xb    = (__hip_bfloat16*)(H + (size_t)2 * NCHUNK * DINNER * DSTATE);
    __hip_bfloat16* xcb   = xb    + (size_t)NTOK * DMODEL;        // 2M bf16
    __hip_bfloat16* gb    = xcb   + (size_t)NTOK * DINNER;        // 4M
    __hip_bfloat16* W1b   = gb    + (size_t)NTOK * DINNER;        // 0.5M
    __hip_bfloat16* w2T   = W1b   + (size_t)DMODEL * DINNER;      // 0.5M
    __hip_bfloat16* convT = w2T   + (size_t)DINNER * DMODEL;      // 4M
    __hip_bfloat16* wdelT = convT + (size_t)4 * DINNER * DINNER;  // 1M
    __hip_bfloat16* woutT = wdelT + (size_t)DINNER * DINNER;      // 0.5M
    __hip_bfloat16* FT    = woutT + (size_t)DINNER * DMODEL;      // 2M (1024 x 2048)

    // input/weight prep
    cvt_slice_k<<<NTOK * DMODEL / 1024, 256, 0, stream>>>(x, xb, DMODEL, DMODEL / 4);
    cvt_slice_k<<<DMODEL * DINNER / 1024, 256, 0, stream>>>(w_in, W1b, 2 * DINNER, DINNER / 4);
    transpose_bf16_k<<<dim3(DINNER / 32, DMODEL / 32), 256, 0, stream>>>(
        w_in + DINNER, w2T, DMODEL, DINNER, 2 * DINNER);
    transpose_bf16_k<<<dim3(DINNER / 32, 4 * DINNER / 32), 256, 0, stream>>>(
        conv_k, convT, 4 * DINNER, DINNER, DINNER);
    transpose_bf16_k<<<dim3(DINNER / 32, DINNER / 32), 256, 0, stream>>>(
        w_del, wdelT, DINNER, DINNER, DINNER);
    transpose_bf16_k<<<dim3(DMODEL / 32, DINNER / 32), 256, 0, stream>>>(
        w_out, woutT, DINNER, DMODEL, DMODEL);

    // fused conv weights: FT[o][tap*512 + dm] = (W1 @ K_tap)[dm][o], row stride 2048
    mgemm<4><<<dim3(DMODEL / BN, DINNER / BM, 4), 256, 0, stream>>>(
        convT, 4 * DINNER, W1b, DINNER, nullptr, FT, 4 * DMODEL, DINNER, nullptr, nullptr);
    // z = x @ W2 (f32)
    mgemm<3><<<dim3(DINNER / BN, NTOK / BM), 256, 0, stream>>>(
        xb, DMODEL, w2T, DMODEL, zbuf, nullptr, DINNER, DMODEL, nullptr, nullptr);
    // x_conv = silu(sum_tap x_shift @ F_tap + conv_b)  (K=2048, FT row stride 2048)
    mgemm<1><<<dim3(DINNER / BN, NTOK / BM), 256, 0, stream>>>(
        xb, DMODEL, FT, 4 * DMODEL, xconv, xcb, DINNER, 4 * DMODEL, conv_b, nullptr);
    // Bm, Cm
    bc_k<<<NTOK, 256, 0, stream>>>(xconv, w_B, b_B, w_C, b_C, Bm, Cm);
    // w = softplus(xc@w_delta+b) * xc * decay
    mgemm<2><<<dim3(DINNER / BN, NTOK / BM), 256, 0, stream>>>(
        xcb, DINNER, wdelT, DINNER, wbuf, nullptr, DINNER, DINNER, b_del, xconv);
    // scan
    chunkS_k<<<dim3(2 * NCHUNK, DINNER / 16), 256, 0, stream>>>(wbuf, Bm, S);
    hpre_k<<<dim3(2 * DINNER * DSTATE / 256), 256, 0, stream>>>(S, H);
    intra_k<<<dim3(2 * NCHUNK, DINNER / 64), 256, 0, stream>>>(wbuf, Bm, Cm, H, zbuf, gb);
    // out = g @ w_out
    mgemm<3><<<dim3(DMODEL / BN, NTOK / BM), 256, 0, stream>>>(
        gb, DINNER, woutT, DINNER, out, nullptr, DMODEL, DINNER, nullptr, nullptr);
}